// Round 1
// baseline (280.127 us; speedup 1.0000x reference)
//
#include <hip/hip_runtime.h>

#define N_NODES 100000
#define D 64

// y[n][j] = sum_k x[n][k] * W[j][k]   (x @ W^T)
__global__ __launch_bounds__(256) void xw_kernel(const float* __restrict__ x,
                                                 const float* __restrict__ W,
                                                 float* __restrict__ y) {
    __shared__ float Ws[D][D + 1];   // +1 pad: lanes read Ws[j][k], stride 65 -> 2-way max (free)
    __shared__ float xs[4][D];

    const int tid = threadIdx.x;
    // cooperative load of W (4096 floats, 16 per thread, coalesced)
    for (int i = tid; i < D * D; i += 256) {
        Ws[i >> 6][i & 63] = W[i];
    }

    const int local = tid >> 6;      // 0..3 (wave id)
    const int j     = tid & 63;      // lane = output feature
    const int node  = blockIdx.x * 4 + local;

    if (node < N_NODES) {
        xs[local][j] = x[node * D + j];
    }
    __syncthreads();

    if (node < N_NODES) {
        float acc = 0.f;
#pragma unroll
        for (int k = 0; k < D; ++k) {
            acc += xs[local][k] * Ws[j][k];   // xs broadcast, Ws conflict-free
        }
        y[node * D + j] = acc;
    }
}

// out[i][j] = b[j]  (float4 stores)
__global__ __launch_bounds__(256) void init_out_kernel(const float* __restrict__ b,
                                                       float* __restrict__ out) {
    const int i = blockIdx.x * blockDim.x + threadIdx.x;   // float4 index
    const int total4 = N_NODES * D / 4;
    if (i < total4) {
        const float4* b4 = reinterpret_cast<const float4*>(b);   // 16 float4s
        reinterpret_cast<float4*>(out)[i] = b4[i & 15];
    }
}

// out[row[e]][j] += val[e] * y[col[e]][j]   (one wave per edge, lane = j)
__global__ __launch_bounds__(256) void scatter_kernel(const int* __restrict__ erow,
                                                      const int* __restrict__ ecol,
                                                      const float* __restrict__ eval_,
                                                      const float* __restrict__ y,
                                                      float* __restrict__ out,
                                                      int n_edges) {
    const int e    = blockIdx.x * 4 + (threadIdx.x >> 6);
    const int lane = threadIdx.x & 63;
    if (e >= n_edges) return;
    const int   r = erow[e];
    const int   c = ecol[e];
    const float v = eval_[e];
    atomicAdd(&out[r * D + lane], v * y[c * D + lane]);
}

extern "C" void kernel_launch(void* const* d_in, const int* in_sizes, int n_in,
                              void* d_out, int out_size, void* d_ws, size_t ws_size,
                              hipStream_t stream) {
    const float* x     = (const float*)d_in[0];
    const int*   erow  = (const int*)  d_in[1];
    const int*   ecol  = (const int*)  d_in[2];
    const float* eval_ = (const float*)d_in[3];
    const float* W     = (const float*)d_in[4];
    const float* b     = (const float*)d_in[5];
    float*       out   = (float*)d_out;
    float*       y     = (float*)d_ws;          // [N_NODES][D] = 25.6 MB scratch

    const int n_edges = in_sizes[1];

    // 1) y = x @ W^T
    xw_kernel<<<(N_NODES + 3) / 4, 256, 0, stream>>>(x, W, y);

    // 2) out = broadcast(b)
    init_out_kernel<<<(N_NODES * D / 4 + 255) / 256, 256, 0, stream>>>(b, out);

    // 3) out[row] += val * y[col]
    scatter_kernel<<<(n_edges + 3) / 4, 256, 0, stream>>>(erow, ecol, eval_, y, out, n_edges);
}

// Round 2
// 267.273 us; speedup vs baseline: 1.0481x; 1.0481x over previous
//
#include <hip/hip_runtime.h>

#define N_NODES 100000
#define D 64

// ---------------- y = x @ W^T ----------------
// 32 nodes per block: W staged once per 32 nodes (vs per 4) -> 8x less W re-read.
__global__ __launch_bounds__(256) void xw_kernel(const float* __restrict__ x,
                                                 const float* __restrict__ W,
                                                 float* __restrict__ y) {
    __shared__ float Ws[D][D + 1];   // stride 65: bank (j+k)&31 -> 2-way max (free)
    __shared__ float xs[32][D];

    const int tid = threadIdx.x;
    for (int i = tid; i < D * D; i += 256) Ws[i >> 6][i & 63] = W[i];

    const int nodeBase = blockIdx.x * 32;
    for (int i = tid; i < 32 * D; i += 256) {
        const int n = nodeBase + (i >> 6);
        xs[i >> 6][i & 63] = (n < N_NODES) ? x[n * D + (i & 63)] : 0.f;
    }
    __syncthreads();

    const int wave = tid >> 6, j = tid & 63;
    for (int s = 0; s < 8; ++s) {
        const int local = wave * 8 + s;
        const int n = nodeBase + local;
        if (n >= N_NODES) break;
        float acc = 0.f;
#pragma unroll
        for (int k = 0; k < D; ++k) acc += xs[local][k] * Ws[j][k];
        y[n * D + j] = acc;
    }
}

// ---------------- CSR build ----------------
__global__ __launch_bounds__(256) void zero_kernel(int* __restrict__ p, int n) {
    const int i = blockIdx.x * 256 + threadIdx.x;
    if (i < n) p[i] = 0;
}

__global__ __launch_bounds__(256) void hist_kernel(const int* __restrict__ erow,
                                                   int* __restrict__ counts, int ne) {
    const int e = blockIdx.x * 256 + threadIdx.x;
    if (e < ne) atomicAdd(&counts[erow[e]], 1);
}

// scan1: per-block (1024 elems) inclusive scan of counts -> off[i+1] (partial), block sums
__global__ __launch_bounds__(256) void scan1_kernel(const int* __restrict__ counts,
                                                    int* __restrict__ off,
                                                    int* __restrict__ bsums, int n) {
    __shared__ int s[256];
    const int base = blockIdx.x * 1024;
    const int tid = threadIdx.x;
    int v[4], sum = 0;
#pragma unroll
    for (int k = 0; k < 4; ++k) {
        const int i = base + tid * 4 + k;
        v[k] = (i < n) ? counts[i] : 0;
        sum += v[k];
    }
    s[tid] = sum;
    __syncthreads();
    for (int d = 1; d < 256; d <<= 1) {
        const int t = (tid >= d) ? s[tid - d] : 0;
        __syncthreads();
        s[tid] += t;
        __syncthreads();
    }
    int run = s[tid] - sum;   // exclusive prefix of this thread within block
#pragma unroll
    for (int k = 0; k < 4; ++k) {
        const int i = base + tid * 4 + k;
        run += v[k];
        if (i < n) off[i + 1] = run;
    }
    if (tid == 255) bsums[blockIdx.x] = s[255];
}

// scan2: single block scans the (<=128) block sums -> exclusive
__global__ __launch_bounds__(128) void scan2_kernel(int* __restrict__ bsums, int nb) {
    __shared__ int s[128];
    const int tid = threadIdx.x;
    const int v = (tid < nb) ? bsums[tid] : 0;
    s[tid] = v;
    __syncthreads();
    for (int d = 1; d < 128; d <<= 1) {
        const int t = (tid >= d) ? s[tid - d] : 0;
        __syncthreads();
        s[tid] += t;
        __syncthreads();
    }
    if (tid < nb) bsums[tid] = s[tid] - v;
}

// scan3: finalize off, derive cursor = row start
__global__ __launch_bounds__(256) void scan3_kernel(int* __restrict__ off,
                                                    int* __restrict__ cursor,
                                                    const int* __restrict__ counts,
                                                    const int* __restrict__ bsums, int n) {
    const int i = blockIdx.x * 256 + threadIdx.x;
    if (i >= n) return;
    const int incl = off[i + 1] + bsums[i >> 10];
    off[i + 1] = incl;
    cursor[i] = incl - counts[i];
    if (i == 0) off[0] = 0;
}

__global__ __launch_bounds__(256) void permute_kernel(const int* __restrict__ erow,
                                                      const int* __restrict__ ecol,
                                                      const float* __restrict__ eval_,
                                                      int* __restrict__ cursor,
                                                      int* __restrict__ pcol,
                                                      float* __restrict__ pval, int ne) {
    const int e = blockIdx.x * 256 + threadIdx.x;
    if (e >= ne) return;
    const int r = erow[e];
    const int pos = atomicAdd(&cursor[r], 1);
    pcol[pos] = ecol[e];
    pval[pos] = eval_[e];
}

// ---------------- aggregate: one wave per row, no atomics ----------------
__global__ __launch_bounds__(256) void aggregate_kernel(const int* __restrict__ off,
                                                        const int* __restrict__ pcol,
                                                        const float* __restrict__ pval,
                                                        const float* __restrict__ y,
                                                        const float* __restrict__ b,
                                                        float* __restrict__ out) {
    const int row  = blockIdx.x * 4 + (threadIdx.x >> 6);
    const int lane = threadIdx.x & 63;
    if (row >= N_NODES) return;
    const int s = off[row], e = off[row + 1];
    float acc = b[lane];
    for (int t = s; t < e; ++t) {
        const int   c = pcol[t];
        const float v = pval[t];
        acc = fmaf(v, y[c * D + lane], acc);
    }
    out[row * D + lane] = acc;
}

// ---------------- fallback (small ws): round-1 atomic scatter ----------------
__global__ __launch_bounds__(256) void init_out_kernel(const float* __restrict__ b,
                                                       float* __restrict__ out) {
    const int i = blockIdx.x * blockDim.x + threadIdx.x;
    const int total4 = N_NODES * D / 4;
    if (i < total4) {
        const float4* b4 = reinterpret_cast<const float4*>(b);
        reinterpret_cast<float4*>(out)[i] = b4[i & 15];
    }
}

__global__ __launch_bounds__(256) void scatter_kernel(const int* __restrict__ erow,
                                                      const int* __restrict__ ecol,
                                                      const float* __restrict__ eval_,
                                                      const float* __restrict__ y,
                                                      float* __restrict__ out, int ne) {
    const int e    = blockIdx.x * 4 + (threadIdx.x >> 6);
    const int lane = threadIdx.x & 63;
    if (e >= ne) return;
    atomicAdd(&out[erow[e] * D + lane], eval_[e] * y[ecol[e] * D + lane]);
}

extern "C" void kernel_launch(void* const* d_in, const int* in_sizes, int n_in,
                              void* d_out, int out_size, void* d_ws, size_t ws_size,
                              hipStream_t stream) {
    const float* x     = (const float*)d_in[0];
    const int*   erow  = (const int*)  d_in[1];
    const int*   ecol  = (const int*)  d_in[2];
    const float* eval_ = (const float*)d_in[3];
    const float* W     = (const float*)d_in[4];
    const float* b     = (const float*)d_in[5];
    float*       out   = (float*)d_out;
    const int ne = in_sizes[1];

    char* ws = (char*)d_ws;
    // workspace layout (256-aligned)
    const size_t Y_OFF      = 0;                 // 25,600,000 B
    const size_t COUNTS_OFF = 25600000;          // 400,000 B
    const size_t OFF_OFF    = 26000128;          // 400,004 B
    const size_t CURSOR_OFF = 26400384;          // 400,000 B
    const size_t PCOL_OFF   = 26800384;          // 4,000,000 B
    const size_t PVAL_OFF   = 30800384;          // 4,000,000 B
    const size_t BSUM_OFF   = 34800384;          // 512 B
    const size_t TOTAL      = 34800896;

    float* y = (float*)(ws + Y_OFF);

    // 1) y = x @ W^T  (100000 = 3125 * 32 exactly)
    xw_kernel<<<3125, 256, 0, stream>>>(x, W, y);

    if (ws_size >= TOTAL) {
        int*   counts = (int*)  (ws + COUNTS_OFF);
        int*   off    = (int*)  (ws + OFF_OFF);
        int*   cursor = (int*)  (ws + CURSOR_OFF);
        int*   pcol   = (int*)  (ws + PCOL_OFF);
        float* pval   = (float*)(ws + PVAL_OFF);
        int*   bsums  = (int*)  (ws + BSUM_OFF);

        zero_kernel<<<(N_NODES + 255) / 256, 256, 0, stream>>>(counts, N_NODES);
        hist_kernel<<<(ne + 255) / 256, 256, 0, stream>>>(erow, counts, ne);

        const int nb = (N_NODES + 1023) / 1024;   // 98
        scan1_kernel<<<nb, 256, 0, stream>>>(counts, off, bsums, N_NODES);
        scan2_kernel<<<1, 128, 0, stream>>>(bsums, nb);
        scan3_kernel<<<(N_NODES + 255) / 256, 256, 0, stream>>>(off, cursor, counts, bsums, N_NODES);

        permute_kernel<<<(ne + 255) / 256, 256, 0, stream>>>(erow, ecol, eval_, cursor, pcol, pval, ne);

        aggregate_kernel<<<(N_NODES + 3) / 4, 256, 0, stream>>>(off, pcol, pval, y, b, out);
    } else {
        // fallback: atomic scatter (round-1 path)
        init_out_kernel<<<(N_NODES * D / 4 + 255) / 256, 256, 0, stream>>>(b, out);
        scatter_kernel<<<(ne + 3) / 4, 256, 0, stream>>>(erow, ecol, eval_, y, out, ne);
    }
}

// Round 3
// 209.511 us; speedup vs baseline: 1.3371x; 1.2757x over previous
//
#include <hip/hip_runtime.h>

#define N_NODES 100000
#define D 64

typedef unsigned int uint32;

__device__ __forceinline__ float bf16_to_f32(unsigned short u) {
    union { unsigned int i; float f; } c; c.i = ((unsigned int)u) << 16; return c.f;
}
__device__ __forceinline__ unsigned short f32_to_bf16(float f) {
    union { float f; unsigned int i; } c; c.f = f;
    const unsigned int u = c.i;
    return (unsigned short)((u + 0x7FFFu + ((u >> 16) & 1u)) >> 16);
}

// ---------------- y = bf16(x @ W^T), plus counts zeroing folded in ----------------
__global__ __launch_bounds__(256) void xw_kernel(const float* __restrict__ x,
                                                 const float* __restrict__ W,
                                                 unsigned short* __restrict__ y,
                                                 int* __restrict__ counts) {
    __shared__ float Ws[D][D + 1];
    __shared__ float xs[32][D];

    const int tid = threadIdx.x;
    const int g = blockIdx.x * 256 + tid;
    if (g < N_NODES) counts[g] = 0;           // hist runs in a later kernel: safe

    for (int i = tid; i < D * D; i += 256) Ws[i >> 6][i & 63] = W[i];

    const int nodeBase = blockIdx.x * 32;
    for (int i = tid; i < 32 * D; i += 256) {
        const int n = nodeBase + (i >> 6);
        xs[i >> 6][i & 63] = (n < N_NODES) ? x[n * D + (i & 63)] : 0.f;
    }
    __syncthreads();

    const int wave = tid >> 6, j = tid & 63;
    for (int s = 0; s < 8; ++s) {
        const int local = wave * 8 + s;
        const int n = nodeBase + local;
        if (n >= N_NODES) break;
        float acc = 0.f;
#pragma unroll
        for (int k = 0; k < D; ++k) acc += xs[local][k] * Ws[j][k];
        y[n * D + j] = f32_to_bf16(acc);
    }
}

// ---------------- CSR build ----------------
__global__ __launch_bounds__(256) void hist_kernel(const int* __restrict__ erow,
                                                   int* __restrict__ counts, int ne) {
    const int e = blockIdx.x * 256 + threadIdx.x;
    if (e < ne) atomicAdd(&counts[erow[e]], 1);
}

__global__ __launch_bounds__(256) void scan1_kernel(const int* __restrict__ counts,
                                                    int* __restrict__ off,
                                                    int* __restrict__ bsums, int n) {
    __shared__ int s[256];
    const int base = blockIdx.x * 1024;
    const int tid = threadIdx.x;
    int v[4], sum = 0;
#pragma unroll
    for (int k = 0; k < 4; ++k) {
        const int i = base + tid * 4 + k;
        v[k] = (i < n) ? counts[i] : 0;
        sum += v[k];
    }
    s[tid] = sum;
    __syncthreads();
    for (int d = 1; d < 256; d <<= 1) {
        const int t = (tid >= d) ? s[tid - d] : 0;
        __syncthreads();
        s[tid] += t;
        __syncthreads();
    }
    int run = s[tid] - sum;
#pragma unroll
    for (int k = 0; k < 4; ++k) {
        const int i = base + tid * 4 + k;
        run += v[k];
        if (i < n) off[i + 1] = run;
    }
    if (tid == 255) bsums[blockIdx.x] = s[255];
}

__global__ __launch_bounds__(128) void scan2_kernel(int* __restrict__ bsums, int nb) {
    __shared__ int s[128];
    const int tid = threadIdx.x;
    const int v = (tid < nb) ? bsums[tid] : 0;
    s[tid] = v;
    __syncthreads();
    for (int d = 1; d < 128; d <<= 1) {
        const int t = (tid >= d) ? s[tid - d] : 0;
        __syncthreads();
        s[tid] += t;
        __syncthreads();
    }
    if (tid < nb) bsums[tid] = s[tid] - v;
}

__global__ __launch_bounds__(256) void scan3_kernel(int* __restrict__ off,
                                                    int* __restrict__ cursor,
                                                    const int* __restrict__ counts,
                                                    const int* __restrict__ bsums, int n) {
    const int i = blockIdx.x * 256 + threadIdx.x;
    if (i >= n) return;
    const int incl = off[i + 1] + bsums[i >> 10];
    off[i + 1] = incl;
    cursor[i] = incl - counts[i];
    if (i == 0) off[0] = 0;
}

// permute: pack (col,val) into one uint32: col<<15 | round(val*32768) (val in [0,1))
__global__ __launch_bounds__(256) void permute_kernel(const int* __restrict__ erow,
                                                      const int* __restrict__ ecol,
                                                      const float* __restrict__ eval_,
                                                      int* __restrict__ cursor,
                                                      uint32* __restrict__ pedge, int ne) {
    const int e = blockIdx.x * 256 + threadIdx.x;
    if (e >= ne) return;
    const int r = erow[e];
    const int pos = atomicAdd(&cursor[r], 1);
    int q = (int)(eval_[e] * 32768.0f + 0.5f);
    q = (q > 32767) ? 32767 : q;
    pedge[pos] = ((uint32)ecol[e] << 15) | (uint32)q;
}

// ---------------- aggregate: 4 quarter-waves per row = 4 concurrent gather chains ----------------
__global__ __launch_bounds__(256) void aggregate_kernel(const int* __restrict__ off,
                                                        const uint32* __restrict__ pedge,
                                                        const unsigned short* __restrict__ y,
                                                        const float* __restrict__ b,
                                                        float4* __restrict__ out4) {
    const int row = blockIdx.x * 4 + (threadIdx.x >> 6);
    if (row >= N_NODES) return;
    const int lane = threadIdx.x & 63;
    const int q = lane >> 4;        // quarter-wave 0..3 -> edge slot
    const int s = lane & 15;        // float4 slot (features 4s..4s+3)
    const int beg = off[row], end = off[row + 1];

    const ushort4* y4 = (const ushort4*)y;   // 4 bf16 = 8B per element; row = 16 elems
    float a0 = 0.f, a1 = 0.f, a2 = 0.f, a3 = 0.f;

    for (int t = beg + q; t < end; t += 4) {
        const uint32 u = pedge[t];
        const int   c = (int)(u >> 15);
        const float v = (float)(u & 32767u) * (1.0f / 32768.0f);
        const ushort4 yv = y4[c * 16 + s];
        a0 = fmaf(v, bf16_to_f32(yv.x), a0);
        a1 = fmaf(v, bf16_to_f32(yv.y), a1);
        a2 = fmaf(v, bf16_to_f32(yv.z), a2);
        a3 = fmaf(v, bf16_to_f32(yv.w), a3);
    }

    // merge the 4 quarter-wave partials (lanes s, s+16, s+32, s+48)
    a0 += __shfl_xor(a0, 16); a1 += __shfl_xor(a1, 16);
    a2 += __shfl_xor(a2, 16); a3 += __shfl_xor(a3, 16);
    a0 += __shfl_xor(a0, 32); a1 += __shfl_xor(a1, 32);
    a2 += __shfl_xor(a2, 32); a3 += __shfl_xor(a3, 32);

    if (q == 0) {
        const float4 bb = ((const float4*)b)[s];
        out4[row * 16 + s] = make_float4(a0 + bb.x, a1 + bb.y, a2 + bb.z, a3 + bb.w);
    }
}

// ---------------- fallback (small ws): atomic scatter ----------------
__global__ __launch_bounds__(256) void init_out_kernel(const float* __restrict__ b,
                                                       float* __restrict__ out) {
    const int i = blockIdx.x * blockDim.x + threadIdx.x;
    const int total4 = N_NODES * D / 4;
    if (i < total4) {
        const float4* b4 = reinterpret_cast<const float4*>(b);
        reinterpret_cast<float4*>(out)[i] = b4[i & 15];
    }
}

__global__ __launch_bounds__(256) void scatter_kernel(const int* __restrict__ erow,
                                                      const int* __restrict__ ecol,
                                                      const float* __restrict__ eval_,
                                                      const unsigned short* __restrict__ y,
                                                      float* __restrict__ out, int ne) {
    const int e    = blockIdx.x * 4 + (threadIdx.x >> 6);
    const int lane = threadIdx.x & 63;
    if (e >= ne) return;
    atomicAdd(&out[erow[e] * D + lane], eval_[e] * bf16_to_f32(y[ecol[e] * D + lane]));
}

extern "C" void kernel_launch(void* const* d_in, const int* in_sizes, int n_in,
                              void* d_out, int out_size, void* d_ws, size_t ws_size,
                              hipStream_t stream) {
    const float* x     = (const float*)d_in[0];
    const int*   erow  = (const int*)  d_in[1];
    const int*   ecol  = (const int*)  d_in[2];
    const float* eval_ = (const float*)d_in[3];
    const float* W     = (const float*)d_in[4];
    const float* b     = (const float*)d_in[5];
    float*       out   = (float*)d_out;
    const int ne = in_sizes[1];

    char* ws = (char*)d_ws;
    // workspace layout (256-aligned)
    const size_t Y_OFF      = 0;                 // 100000*64*2 = 12,800,000 B (bf16)
    const size_t COUNTS_OFF = 12800000;          // 400,000 B
    const size_t OFF_OFF    = 13200128;          // 400,004 B
    const size_t CURSOR_OFF = 13600384;          // 400,000 B
    const size_t PEDGE_OFF  = 14000384;          // 4,000,000 B
    const size_t BSUM_OFF   = 18000384;          // 512 B
    const size_t TOTAL      = 18000896;

    unsigned short* y = (unsigned short*)(ws + Y_OFF);

    if (ws_size >= TOTAL) {
        int*    counts = (int*)   (ws + COUNTS_OFF);
        int*    off    = (int*)   (ws + OFF_OFF);
        int*    cursor = (int*)   (ws + CURSOR_OFF);
        uint32* pedge  = (uint32*)(ws + PEDGE_OFF);
        int*    bsums  = (int*)   (ws + BSUM_OFF);

        // 1) y = bf16(x @ W^T); also zeroes counts
        xw_kernel<<<3125, 256, 0, stream>>>(x, W, y, counts);

        // 2) CSR build
        hist_kernel<<<(ne + 255) / 256, 256, 0, stream>>>(erow, counts, ne);
        const int nb = (N_NODES + 1023) / 1024;   // 98
        scan1_kernel<<<nb, 256, 0, stream>>>(counts, off, bsums, N_NODES);
        scan2_kernel<<<1, 128, 0, stream>>>(bsums, nb);
        scan3_kernel<<<(N_NODES + 255) / 256, 256, 0, stream>>>(off, cursor, counts, bsums, N_NODES);
        permute_kernel<<<(ne + 255) / 256, 256, 0, stream>>>(erow, ecol, eval_, cursor, pedge, ne);

        // 3) aggregate (gather, no atomics) + bias
        aggregate_kernel<<<(N_NODES + 3) / 4, 256, 0, stream>>>(off, pedge, y, b, (float4*)out);
    } else {
        xw_kernel<<<3125, 256, 0, stream>>>(x, W, y, (int*)(ws + COUNTS_OFF));
        init_out_kernel<<<(N_NODES * D / 4 + 255) / 256, 256, 0, stream>>>(b, out);
        scatter_kernel<<<(ne + 3) / 4, 256, 0, stream>>>(erow, ecol, eval_, y, out, ne);
    }
}